// Round 3
// baseline (145.255 us; speedup 1.0000x reference)
//
#include <hip/hip_runtime.h>

#define M_ROWS 8192   // B*L
#define DIM    768    // D
#define HCH    128    // H

typedef __bf16 bf16x8 __attribute__((ext_vector_type(8)));
typedef float  f32x4  __attribute__((ext_vector_type(4)));

__device__ __forceinline__ unsigned short f2bf(float f) {
    union { float f; unsigned int u; } v; v.f = f;
    unsigned int u = v.u;
    u += 0x7fffu + ((u >> 16) & 1u);   // round-to-nearest-even
    return (unsigned short)(u >> 16);
}
__device__ __forceinline__ unsigned int pk2bf(float x, float y) {
    return (unsigned int)f2bf(x) | ((unsigned int)f2bf(y) << 16);
}

// W0 f32 [128][768] -> bf16 [128][768] (already the B^T layout MFMA wants).
// Done once so the 512 gemm blocks re-read 192 KB (bf16) instead of 384 KB
// (f32) each: 98 MB vs 196 MB of L2 traffic, and no pack-VALU in the K-loop.
__global__ __launch_bounds__(256) void convert_w0_kernel(
    const float* __restrict__ W0, unsigned short* __restrict__ W0b)
{
    int i = (blockIdx.x * 256 + threadIdx.x) * 4;   // 98304 / 4 = 24576 threads
    float4 v = *(const float4*)(W0 + i);
    uint2 o;
    o.x = pk2bf(v.x, v.y);
    o.y = pk2bf(v.z, v.w);
    *(uint2*)(W0b + i) = o;
}

// Fused GEMM (M=8192,N=128,K=768 bf16 MFMA) + relu + weighted H-reduction.
// Block: 256 thr = 4 waves; each wave owns a 32-col strip of all 16 rows.
// Grid: 512 (16 rows/block) -> 2 blocks/CU, 8 waves/CU.
// BK=64: 12 K-iterations (halves barrier-drain count vs BK=32).
__global__ __launch_bounds__(256) void gemm_s_kernel(
    const float* __restrict__ text,
    const unsigned short* __restrict__ W0b,
    const float* __restrict__ b0,
    const float* __restrict__ W1,
    float* __restrict__ s1, float* __restrict__ s2)
{
    // row stride 72 bf16 = 144 B: b128 frag reads alias only 2-way (free)
    __shared__ unsigned short As[16][72];
    __shared__ unsigned short Bs[128][72];
    __shared__ float red1[16][4];
    __shared__ float red2[16][4];

    const int tid  = threadIdx.x;
    const int lane = tid & 63;
    const int wave = tid >> 6;
    const int row0 = blockIdx.x * 16;

    const int n16  = lane & 15;
    const int quad = lane >> 4;
    const int wcol = wave * 32;          // this wave's 32-col strip

    // staging maps (BK = 64)
    const int ar = tid >> 4;             // A: 16 rows x 64 k f32 = 1 float4/thr
    const int ak = (tid & 15) << 2;
    const int br = tid >> 3;             // B: 128 rows x 64 k bf16, 4 uint4/thr
    const int bk = (tid & 7) << 3;       //   rows br, br+32, br+64, br+96

    const float*          aptr = text + (size_t)(row0 + ar) * DIM + ak;
    const unsigned short* bptr = W0b + (size_t)br * DIM + bk;

    f32x4 acc[2];
    acc[0] = (f32x4){0.f, 0.f, 0.f, 0.f};
    acc[1] = (f32x4){0.f, 0.f, 0.f, 0.f};

    float4 av;
    uint4  bv[4];
    av = *(const float4*)aptr;
    #pragma unroll
    for (int q = 0; q < 4; ++q) bv[q] = *(const uint4*)(bptr + (size_t)q * 32 * DIM);

    for (int kt = 0; kt < DIM; kt += 64) {
        const int ktn = (kt + 64 < DIM) ? (kt + 64) : 0;   // harmless reload on last iter
        float4 av_n;
        uint4  bv_n[4];
        av_n = *(const float4*)(aptr + ktn);
        #pragma unroll
        for (int q = 0; q < 4; ++q)
            bv_n[q] = *(const uint4*)(bptr + ktn + (size_t)q * 32 * DIM);

        // stage current tile into LDS (A: f32 -> bf16 on the fly; B: raw copy)
        {
            uint2 o;
            o.x = pk2bf(av.x, av.y);
            o.y = pk2bf(av.z, av.w);
            *(uint2*)&As[ar][ak] = o;
        }
        #pragma unroll
        for (int q = 0; q < 4; ++q)
            *(uint4*)&Bs[br + q * 32][bk] = bv[q];
        __syncthreads();

        bf16x8 a0 = *(const bf16x8*)&As[n16][quad * 8];
        bf16x8 a1 = *(const bf16x8*)&As[n16][32 + quad * 8];
        bf16x8 b00 = *(const bf16x8*)&Bs[wcol +  0 + n16][quad * 8];
        bf16x8 b01 = *(const bf16x8*)&Bs[wcol +  0 + n16][32 + quad * 8];
        bf16x8 b10 = *(const bf16x8*)&Bs[wcol + 16 + n16][quad * 8];
        bf16x8 b11 = *(const bf16x8*)&Bs[wcol + 16 + n16][32 + quad * 8];
        acc[0] = __builtin_amdgcn_mfma_f32_16x16x32_bf16(a0, b00, acc[0], 0, 0, 0);
        acc[1] = __builtin_amdgcn_mfma_f32_16x16x32_bf16(a0, b10, acc[1], 0, 0, 0);
        acc[0] = __builtin_amdgcn_mfma_f32_16x16x32_bf16(a1, b01, acc[0], 0, 0, 0);
        acc[1] = __builtin_amdgcn_mfma_f32_16x16x32_bf16(a1, b11, acc[1], 0, 0, 0);
        __syncthreads();

        av = av_n;
        #pragma unroll
        for (int q = 0; q < 4; ++q) bv[q] = bv_n[q];
    }

    // epilogue: relu + b0, weight by w_a / w_b, reduce this wave's 32 cols.
    // C/D layout (verified): col = lane&15 (+tile), row = quad*4 + reg
    float p1[4] = {0.f, 0.f, 0.f, 0.f};
    float p2[4] = {0.f, 0.f, 0.f, 0.f};
    #pragma unroll
    for (int j = 0; j < 2; ++j) {
        const int col = wcol + j * 16 + n16;
        const float bb = b0[col];
        const float wa = W1[col];
        const float wb = W1[HCH + col];
        #pragma unroll
        for (int r = 0; r < 4; ++r) {
            float h = acc[j][r] + bb;
            h = fmaxf(h, 0.f);
            p1[r] += h * wa;
            p2[r] += h * wb;
        }
    }
    // reduce across the 16 lanes of each quad (masks < 16 stay inside the quad)
    #pragma unroll
    for (int r = 0; r < 4; ++r) {
        #pragma unroll
        for (int m = 8; m >= 1; m >>= 1) {
            p1[r] += __shfl_xor(p1[r], m);
            p2[r] += __shfl_xor(p2[r], m);
        }
    }
    if (n16 == 0) {
        #pragma unroll
        for (int r = 0; r < 4; ++r) {
            const int rr = quad * 4 + r;      // row within the 16
            red1[rr][wave] = p1[r];
            red2[rr][wave] = p2[r];
        }
    }
    __syncthreads();
    if (tid < 16) {
        s1[row0 + tid] = red1[tid][0] + red1[tid][1] + red1[tid][2] + red1[tid][3];
        s2[row0 + tid] = red2[tid][0] + red2[tid][1] + red2[tid][2] + red2[tid][3];
    }
}

// out[b][i][j] = sigmoid(s1[b*1024+i] + s2[b*1024+j] + b1)
// grid = 8192 (one block per (b,i) row), 256 thr x float4 = 1024 j's
__global__ __launch_bounds__(256) void outer_sigmoid_kernel(
    const float* __restrict__ s1, const float* __restrict__ s2,
    const float* __restrict__ b1, float* __restrict__ out)
{
    const int bi = blockIdx.x;
    const int b  = bi >> 10;
    const float base = s1[bi] + b1[0];
    const float4 t = ((const float4*)(s2 + (b << 10)))[threadIdx.x];
    float4 r;
    r.x = 1.f / (1.f + __expf(-(base + t.x)));
    r.y = 1.f / (1.f + __expf(-(base + t.y)));
    r.z = 1.f / (1.f + __expf(-(base + t.z)));
    r.w = 1.f / (1.f + __expf(-(base + t.w)));
    ((float4*)out)[((size_t)bi << 8) + threadIdx.x] = r;
}

extern "C" void kernel_launch(void* const* d_in, const int* in_sizes, int n_in,
                              void* d_out, int out_size, void* d_ws, size_t ws_size,
                              hipStream_t stream)
{
    const float* text = (const float*)d_in[0];
    // d_in[1] = mask: all-ones, unused by the reference math
    const float* W0 = (const float*)d_in[2];
    const float* b0 = (const float*)d_in[3];
    const float* W1 = (const float*)d_in[4];
    const float* b1 = (const float*)d_in[5];
    float* out = (float*)d_out;

    // workspace layout: [W0b bf16: 192 KB][s1: 32 KB][s2: 32 KB]
    unsigned short* W0b = (unsigned short*)d_ws;
    float* s1 = (float*)((char*)d_ws + (size_t)HCH * DIM * sizeof(unsigned short));
    float* s2 = s1 + M_ROWS;

    convert_w0_kernel<<<96, 256, 0, stream>>>(W0, W0b);
    gemm_s_kernel<<<512, 256, 0, stream>>>(text, W0b, b0, W1, s1, s2);
    outer_sigmoid_kernel<<<8192, 256, 0, stream>>>(s1, s2, b1, out);
}

// Round 4
// 102.536 us; speedup vs baseline: 1.4166x; 1.4166x over previous
//
#include <hip/hip_runtime.h>

#define M_ROWS 8192   // B*L
#define DIM    768    // D
#define HCH    128    // H
#define KSTEPS 24     // 768 / 32

typedef __bf16 bf16x8 __attribute__((ext_vector_type(8)));
typedef float  f32x4  __attribute__((ext_vector_type(4)));

// W0 f32 [128][768] -> bf16 in MFMA B-fragment-major layout:
//   W0f[((colTile*KSTEPS + kStep)*64 + lane)] = 8 bf16 =
//   W0[colTile*16 + (lane&15)][kStep*32 + (lane>>4)*8 + j], j=0..7
// so the gemm's B-frag load is ONE coalesced dwordx4 per tile per k-step.
__global__ __launch_bounds__(256) void convert_w0_frag(
    const float* __restrict__ W0, bf16x8* __restrict__ W0f)
{
    const int g    = blockIdx.x * 256 + threadIdx.x;   // 8*24*64 = 12288 total
    const int c    = g / (KSTEPS * 64);
    const int r    = g - c * (KSTEPS * 64);
    const int s    = r >> 6;
    const int lane = r & 63;
    const int n16  = lane & 15;
    const int quad = lane >> 4;
    const float* src = W0 + (size_t)(c * 16 + n16) * DIM + s * 32 + quad * 8;
    float4 v0 = *(const float4*)src;
    float4 v1 = *(const float4*)(src + 4);
    bf16x8 o;
    o[0] = (__bf16)v0.x; o[1] = (__bf16)v0.y; o[2] = (__bf16)v0.z; o[3] = (__bf16)v0.w;
    o[4] = (__bf16)v1.x; o[5] = (__bf16)v1.y; o[6] = (__bf16)v1.z; o[7] = (__bf16)v1.w;
    W0f[g] = o;
}

// Barrier-free, LDS-free fused GEMM (M=8192,N=128,K=768 bf16 MFMA) + relu +
// weighted H-reduction. Block = 4 waves, all covering the SAME 16 rows
// (shared A lines hit L1); wave w owns col strip w*32 (colTiles 2w, 2w+1).
// Grid 512 blocks -> 2048 waves -> 8 waves/CU. No __syncthreads in the
// K-loop => no vmcnt(0) drains; depth-2 register pipeline keeps loads in
// flight across steps.
__global__ __launch_bounds__(256) void gemm_s_kernel(
    const float* __restrict__ text,
    const bf16x8* __restrict__ W0f,
    const float* __restrict__ b0,
    const float* __restrict__ W1,
    float* __restrict__ s1, float* __restrict__ s2)
{
    __shared__ float red1[16][4];
    __shared__ float red2[16][4];

    const int tid  = threadIdx.x;
    const int lane = tid & 63;
    const int wave = tid >> 6;
    const int n16  = lane & 15;
    const int quad = lane >> 4;
    const int row0 = blockIdx.x * 16;
    const int c0   = wave * 2;           // this wave's two 16-col tiles

    // A: lane holds A[row=n16][k = kt + quad*8 .. +7] (f32, converted on use).
    // The 4 quads of 16 lanes cover one full 128B line per row; all 4 waves
    // read the same lines -> L1 reuse.
    const float*  aptr  = text + (size_t)(row0 + n16) * DIM + quad * 8;
    const bf16x8* bptr0 = W0f + (size_t)(c0    ) * KSTEPS * 64 + lane;
    const bf16x8* bptr1 = W0f + (size_t)(c0 + 1) * KSTEPS * 64 + lane;

    f32x4 acc0 = (f32x4){0.f, 0.f, 0.f, 0.f};
    f32x4 acc1 = (f32x4){0.f, 0.f, 0.f, 0.f};

    // 3-slot rolling pipeline, prefetch depth 2
    float4 a0[3], a1[3];
    bf16x8 bv0[3], bv1[3];
    #pragma unroll
    for (int s = 0; s < 2; ++s) {
        a0[s]  = *(const float4*)(aptr + s * 32);
        a1[s]  = *(const float4*)(aptr + s * 32 + 4);
        bv0[s] = bptr0[s * 64];
        bv1[s] = bptr1[s * 64];
    }

    #pragma unroll
    for (int s = 0; s < KSTEPS; ++s) {
        const int sl = s % 3;
        const int pl = (s + 2) % 3;
        const int sp = (s + 2 < KSTEPS) ? (s + 2) : (s + 2 - KSTEPS); // harmless wrap
        a0[pl]  = *(const float4*)(aptr + sp * 32);
        a1[pl]  = *(const float4*)(aptr + sp * 32 + 4);
        bv0[pl] = bptr0[sp * 64];
        bv1[pl] = bptr1[sp * 64];

        bf16x8 af;
        af[0] = (__bf16)a0[sl].x; af[1] = (__bf16)a0[sl].y;
        af[2] = (__bf16)a0[sl].z; af[3] = (__bf16)a0[sl].w;
        af[4] = (__bf16)a1[sl].x; af[5] = (__bf16)a1[sl].y;
        af[6] = (__bf16)a1[sl].z; af[7] = (__bf16)a1[sl].w;
        acc0 = __builtin_amdgcn_mfma_f32_16x16x32_bf16(af, bv0[sl], acc0, 0, 0, 0);
        acc1 = __builtin_amdgcn_mfma_f32_16x16x32_bf16(af, bv1[sl], acc1, 0, 0, 0);
    }

    // epilogue: relu + b0, weight by w_a / w_b, reduce this wave's 32 cols.
    // C/D layout (verified): col = lane&15 (+tile*16), row = quad*4 + reg
    float p1[4] = {0.f, 0.f, 0.f, 0.f};
    float p2[4] = {0.f, 0.f, 0.f, 0.f};
    #pragma unroll
    for (int j = 0; j < 2; ++j) {
        const f32x4 aj = j ? acc1 : acc0;
        const int col = wave * 32 + j * 16 + n16;
        const float bb = b0[col];
        const float wa = W1[col];
        const float wb = W1[HCH + col];
        #pragma unroll
        for (int r = 0; r < 4; ++r) {
            float h = aj[r] + bb;
            h = fmaxf(h, 0.f);
            p1[r] += h * wa;
            p2[r] += h * wb;
        }
    }
    // reduce across the 16 lanes of each quad (masks < 16 stay inside the quad)
    #pragma unroll
    for (int r = 0; r < 4; ++r) {
        #pragma unroll
        for (int m = 8; m >= 1; m >>= 1) {
            p1[r] += __shfl_xor(p1[r], m);
            p2[r] += __shfl_xor(p2[r], m);
        }
    }
    if (n16 == 0) {
        #pragma unroll
        for (int r = 0; r < 4; ++r) {
            const int rr = quad * 4 + r;      // row within the 16
            red1[rr][wave] = p1[r];
            red2[rr][wave] = p2[r];
        }
    }
    __syncthreads();
    if (tid < 16) {
        s1[row0 + tid] = red1[tid][0] + red1[tid][1] + red1[tid][2] + red1[tid][3];
        s2[row0 + tid] = red2[tid][0] + red2[tid][1] + red2[tid][2] + red2[tid][3];
    }
}

// out[b][i][j] = sigmoid(s1[b*1024+i] + s2[b*1024+j] + b1)
// grid = 8192 (one block per (b,i) row), 256 thr x float4 = 1024 j's
__global__ __launch_bounds__(256) void outer_sigmoid_kernel(
    const float* __restrict__ s1, const float* __restrict__ s2,
    const float* __restrict__ b1, float* __restrict__ out)
{
    const int bi = blockIdx.x;
    const int b  = bi >> 10;
    const float base = s1[bi] + b1[0];
    const float4 t = ((const float4*)(s2 + (b << 10)))[threadIdx.x];
    float4 r;
    r.x = 1.f / (1.f + __expf(-(base + t.x)));
    r.y = 1.f / (1.f + __expf(-(base + t.y)));
    r.z = 1.f / (1.f + __expf(-(base + t.z)));
    r.w = 1.f / (1.f + __expf(-(base + t.w)));
    ((float4*)out)[((size_t)bi << 8) + threadIdx.x] = r;
}

extern "C" void kernel_launch(void* const* d_in, const int* in_sizes, int n_in,
                              void* d_out, int out_size, void* d_ws, size_t ws_size,
                              hipStream_t stream)
{
    const float* text = (const float*)d_in[0];
    // d_in[1] = mask: all-ones, unused by the reference math
    const float* W0 = (const float*)d_in[2];
    const float* b0 = (const float*)d_in[3];
    const float* W1 = (const float*)d_in[4];
    const float* b1 = (const float*)d_in[5];
    float* out = (float*)d_out;

    // workspace layout: [W0f bf16 frags: 192 KB][s1: 32 KB][s2: 32 KB]
    bf16x8* W0f = (bf16x8*)d_ws;
    float* s1 = (float*)((char*)d_ws + (size_t)HCH * DIM * sizeof(unsigned short));
    float* s2 = s1 + M_ROWS;

    convert_w0_frag<<<48, 256, 0, stream>>>(W0, W0f);
    gemm_s_kernel<<<512, 256, 0, stream>>>(text, W0f, b0, W1, s1, s2);
    outer_sigmoid_kernel<<<8192, 256, 0, stream>>>(s1, s2, b1, out);
}